// Round 14
// baseline (417.578 us; speedup 1.0000x reference)
//
#include <hip/hip_runtime.h>
#include <stdint.h>
#include <stddef.h>

// z = x[32768,512] @ W[2048,512]^T + B; per-row instance-norm over 2048;
// out = (z_norm + y) * y.  f32 I/O; GEMM in INT8 MFMA (32x32x16_i8).
//
// Round-14: in-block generation pipeline with ZERO cross-phase registers
// (r2-r7's failure = scratch spill, diagnosed r13):
//  - x pre-quantized to int8 in ws (xq_pre) -> A-tiles via global_load_lds
//  - z(g) packed to bf16 in 64 regs at stats(g), freeing the 128 acc AGPRs
//  - K(g+1)'s 32 chunks each interleave 4 epilogue(g) units (y prefetch
//    1 chunk deep, full-line frag stores) -> L2 W-stream overlaps HBM stream
//  - grid 256 = 1 block/CU exactly, GENS=4, 8 waves, LDS 98816 B
// Fallback: proven round-12 kernel if ws too small.

typedef float  f32x4  __attribute__((ext_vector_type(4)));
typedef int    i32x16 __attribute__((ext_vector_type(16)));

#define BATCH   32768
#define INF     512
#define OUTF    2048
#define THREADS 512

// workspace layout
#define WQ_OFF  0u
#define SW_OFF  1048576u
#define XQ_OFF  2097152u           // 16 MB int8 x (quantized, A-image layout)
#define SXG_OFF 18874368u          // 32768 f32 row scales
#define WS_BIG  19005440u
#define WS_SMALL (1048576u + 8192u)

// big-kernel LDS
#define AB_OFF   0                 // 2 x 16384 A tiles (int8); stats overlay post-K
#define WB_OFF   32768             // 2 x 32768 W chunk buffers
#define RS_OFF   98304             // 2 x [32][2] f32 rowstat
#define SMEM_BIG 98816

__device__ __forceinline__ f32x4 ld4(const float* p) { return *(const f32x4*)p; }

__device__ __forceinline__ void glds16(const void* g, void* l) {
    __builtin_amdgcn_global_load_lds(
        (const __attribute__((address_space(1))) unsigned int*)g,
        (__attribute__((address_space(3))) unsigned int*)l, 16, 0, 0);
}

__device__ __forceinline__ unsigned short f2bf(float f) {
    unsigned int u = __builtin_bit_cast(unsigned int, f);
    u += 0x7FFFu + ((u >> 16) & 1u);     // RNE
    return (unsigned short)(u >> 16);
}

__device__ __forceinline__ long long quant8(f32x4 a, f32x4 b, float inv) {
    unsigned int lo = 0, hi = 0;
    int q;
    q = (int)__builtin_rintf(a[0] * inv); lo |= (unsigned)(q & 255);
    q = (int)__builtin_rintf(a[1] * inv); lo |= (unsigned)(q & 255) << 8;
    q = (int)__builtin_rintf(a[2] * inv); lo |= (unsigned)(q & 255) << 16;
    q = (int)__builtin_rintf(a[3] * inv); lo |= (unsigned)(q & 255) << 24;
    q = (int)__builtin_rintf(b[0] * inv); hi |= (unsigned)(q & 255);
    q = (int)__builtin_rintf(b[1] * inv); hi |= (unsigned)(q & 255) << 8;
    q = (int)__builtin_rintf(b[2] * inv); hi |= (unsigned)(q & 255) << 16;
    q = (int)__builtin_rintf(b[3] * inv); hi |= (unsigned)(q & 255) << 24;
    return (long long)(((unsigned long long)hi << 32) | lo);
}

// Prepass 1 (r12-proven): W f32 [2048,512] -> Wq int8, 32 chunks of 32 KB,
// chunk s interior: half*16384 + w*2048 + n*256 + c31*8  (col = n*256+w*32+c31,
// k = s*16 + half*8 + j) + per-col scales sw[2048].
__global__ __launch_bounds__(64) void conv_w_kernel(const float* __restrict__ W,
                                                    char* __restrict__ Wq,
                                                    float* __restrict__ sw) {
    const int o = blockIdx.x;
    const int l = threadIdx.x;
    const float* src = W + (size_t)o * INF + l * 8;
    f32x4 a = ld4(src), b = ld4(src + 4);
    float m = 0.f;
    #pragma unroll
    for (int j = 0; j < 4; ++j) m = fmaxf(m, fmaxf(fabsf(a[j]), fabsf(b[j])));
    #pragma unroll
    for (int d = 1; d < 64; d <<= 1) m = fmaxf(m, __shfl_xor(m, d));
    const float inv = m > 0.f ? 127.0f / m : 0.f;
    long long v = quant8(a, b, inv);
    const int s = l >> 1, half = l & 1;
    size_t off = (size_t)s * 32768 + half * 16384 +
                 ((o >> 5) & 7) * 2048 + (o >> 8) * 256 + (o & 31) * 8;
    *(long long*)(Wq + off) = v;
    if (l == 0) sw[o] = m > 0.f ? m * (1.0f / 127.0f) : 0.f;
}

// Prepass 2: x f32 -> xq int8 in the A-tile LDS image: per 32-row block rb,
// xq[rb][k8][row][8] (16 KB) + sxg row scales.  Coalesced reads; writes merge
// at 64B-sector granularity within each instruction.
__global__ __launch_bounds__(256) void xq_pre(const float* __restrict__ x,
                                              char* __restrict__ xq,
                                              float* __restrict__ sxg) {
    const int rb = blockIdx.x;
    const int t = threadIdx.x;
    const int row = t >> 3;
    const int i = t & 7;
    const float* src = x + ((size_t)rb * 32 + row) * 512 + i * 64;
    f32x4 v[16];
    #pragma unroll
    for (int j = 0; j < 16; ++j) v[j] = ld4(src + j * 4);
    float m = 0.f;
    #pragma unroll
    for (int j = 0; j < 16; ++j)
        #pragma unroll
        for (int e = 0; e < 4; ++e) m = fmaxf(m, fabsf(v[j][e]));
    #pragma unroll
    for (int d = 1; d < 8; d <<= 1) m = fmaxf(m, __shfl_xor(m, d));
    const float inv = m > 0.f ? 127.0f / m : 0.f;
    if (i == 0) sxg[rb * 32 + row] = m > 0.f ? m * (1.0f / 127.0f) : 0.f;
    char* dst = xq + (size_t)rb * 16384 + row * 8;
    #pragma unroll
    for (int jj = 0; jj < 8; ++jj)
        *(long long*)(dst + (i * 8 + jj) * 256) = quant8(v[2 * jj], v[2 * jj + 1], inv);
}

// A-frag (32x32x16_i8): lane l -> A[row=l&31][k = s*16 + (l>>5)*8 + j]
// C-frag: col = lane&31, row = (q&3) + 8*(q>>2) + 4*(lane>>5), q=0..15
// Wave w owns cols col(n) = n*256 + w*32 + c31, n=0..7.
__global__ __launch_bounds__(THREADS, 2) void fused_big(
    const float* __restrict__ y, const float* __restrict__ Bias,
    const char* __restrict__ Wq, const float* __restrict__ sw,
    const char* __restrict__ xq, const float* __restrict__ sxg,
    float* __restrict__ out) {

    __shared__ __align__(16) char smem[SMEM_BIG];

    const int t = threadIdx.x;
    const int w = t >> 6;
    const int l = t & 63;
    const int c31 = l & 31;
    const int half = l >> 5;
    const int rb0 = blockIdx.x * 4;
    const int m00 = blockIdx.x * 128;

    // prologue: A(0) -> Abuf0 ; W chunk 0 -> Wbuf0
    #pragma unroll
    for (int i = 0; i < 2; ++i)
        glds16(xq + (size_t)rb0 * 16384 + i * 8192 + t * 16,
               smem + AB_OFF + i * 8192 + w * 1024);
    #pragma unroll
    for (int i = 0; i < 4; ++i)
        glds16(Wq + i * 8192 + t * 16,
               smem + WB_OFF + i * 8192 + w * 1024);

    float    ypf[2][4];     // y prefetch, 1 chunk deep (static parity)
    unsigned zz[8][8];      // z(g) packed bf16: [n][q>>1], low=even q
    i32x16   acc[8];

    for (int g = 0; g < 4; ++g) {
        const int m0 = m00 + g * 32;
        const char* Ab = smem + AB_OFF + ((g & 1) << 14);

        #pragma unroll
        for (int n = 0; n < 8; ++n) acc[n] = (i32x16)(0);

        #pragma unroll
        for (int c = 0; c < 32; ++c) {
            __asm__ volatile("s_waitcnt vmcnt(0)" ::: "memory");  // chunk c + y landed
            __builtin_amdgcn_s_barrier();

            // issue next W chunk (wraps to next gen's chunk 0)
            if (!(g == 3 && c == 31)) {
                const int nc = (c + 1) & 31;
                #pragma unroll
                for (int i = 0; i < 4; ++i)
                    glds16(Wq + (size_t)nc * 32768 + i * 8192 + t * 16,
                           smem + WB_OFF + (((c + 1) & 1) << 15) + i * 8192 + w * 1024);
            }
            // stage A(g+1) (zero registers)
            if (c == 0 && g < 3) {
                #pragma unroll
                for (int i = 0; i < 2; ++i)
                    glds16(xq + (size_t)(rb0 + g + 1) * 16384 + i * 8192 + t * 16,
                           smem + AB_OFF + (((g + 1) & 1) << 14) + i * 8192 + w * 1024);
            }
            // y prefetch for units consumed next chunk
            {
                const int gp = (c < 31) ? (g - 1) : g;
                if (gp >= 0 && !(g == 3 && c == 31)) {
                    const int uc = (c + 1) & 31;
                    const int q = uc >> 1;
                    const size_t roff =
                        (size_t)(m00 + gp * 32 + (q & 3) + 8 * (q >> 2)) * 2048 +
                        (size_t)half * 8192 + w * 32 + c31;
                    #pragma unroll
                    for (int k = 0; k < 4; ++k)
                        ypf[(c + 1) & 1][k] = y[roff + ((uc & 1) * 4 + k) * 256];
                }
            }
            // epilogue(g-1): 4 units (q = c>>1, n = (c&1)*4+k); full-line stores
            if (g >= 1) {
                const int q = c >> 1;
                const int r = (q & 3) + 8 * (q >> 2) + 4 * half;
                const float* rs = (const float*)(smem + RS_OFF + (((g - 1) & 1) << 8));
                const float mean = rs[r * 2];
                const float rstd = rs[r * 2 + 1];
                const size_t roff =
                    (size_t)(m00 + (g - 1) * 32 + (q & 3) + 8 * (q >> 2)) * 2048 +
                    (size_t)half * 8192 + w * 32 + c31;
                #pragma unroll
                for (int k = 0; k < 4; ++k) {
                    const int n = (c & 1) * 4 + k;
                    const unsigned hz =
                        ((zz[n][c >> 2] >> (16 * ((c >> 1) & 1))) & 0xffffu) << 16;
                    const float zf = __builtin_bit_cast(float, hz);
                    const float yv = ypf[c & 1][k];
                    const float zn = (zf - mean) * rstd;
                    out[roff + n * 256] = (zn + yv) * yv;
                }
            }
            // K compute: 1 A-read + 8 B-reads + 8 MFMA
            {
                const int k8 = 2 * c + half;
                const long long af = *(const long long*)(Ab + (k8 << 8) + (c31 << 3));
                const char* bb = smem + WB_OFF + ((c & 1) << 15) +
                                 half * 16384 + w * 2048 + c31 * 8;
                #pragma unroll
                for (int n = 0; n < 8; ++n)
                    acc[n] = __builtin_amdgcn_mfma_i32_32x32x16_i8(
                        af, *(const long long*)(bb + n * 256), acc[n], 0, 0, 0);
            }
        }

        // ---- stats(g): dequant, stats, pack z->bf16 (frees acc) ----
        __asm__ volatile("s_waitcnt lgkmcnt(0)" ::: "memory");
        __builtin_amdgcn_s_barrier();      // all A(g) reads done -> overlay safe

        float swv[8], bsv[8];
        #pragma unroll
        for (int n = 0; n < 8; ++n) {
            const int col = n * 256 + w * 32 + c31;
            swv[n] = sw[col];
            bsv[n] = Bias[col];
        }
        float* stats = (float*)(smem + AB_OFF + ((g & 1) << 14));  // overlay A(g)
        #pragma unroll
        for (int q = 0; q < 16; ++q) {
            const int r = (q & 3) + 8 * (q >> 2) + 4 * half;
            const float sx = sxg[m0 + r];
            float s1 = 0.f, s2 = 0.f;
            #pragma unroll
            for (int n = 0; n < 8; ++n) {
                const float zf = fmaf((float)acc[n][q], sx * swv[n], bsv[n]);
                s1 += zf; s2 += zf * zf;
                const unsigned short h = f2bf(zf);
                if (q & 1) zz[n][q >> 1] |= (unsigned)h << 16;
                else       zz[n][q >> 1]  = h;
            }
            #pragma unroll
            for (int d = 1; d < 32; d <<= 1) {
                s1 += __shfl_xor(s1, d);
                s2 += __shfl_xor(s2, d);
            }
            if (c31 == 0) {
                stats[(w * 32 + r) * 2]     = s1;
                stats[(w * 32 + r) * 2 + 1] = s2;
            }
        }
        __asm__ volatile("s_waitcnt lgkmcnt(0)" ::: "memory");
        __builtin_amdgcn_s_barrier();
        if (t < 32) {
            float s1 = 0.f, s2 = 0.f;
            #pragma unroll
            for (int wi = 0; wi < 8; ++wi) {
                s1 += stats[(wi * 32 + t) * 2];
                s2 += stats[(wi * 32 + t) * 2 + 1];
            }
            const float mean = s1 * (1.0f / OUTF);
            const float var  = s2 * (1.0f / OUTF) - mean * mean;
            float* rs = (float*)(smem + RS_OFF + ((g & 1) << 8));
            rs[t * 2]     = mean;
            rs[t * 2 + 1] = rsqrtf(var + 1e-5f);
        }
        __asm__ volatile("s_waitcnt lgkmcnt(0)" ::: "memory");
        __builtin_amdgcn_s_barrier();
    }

    // ---- epilogue(3) standalone ----
    const int m3 = m00 + 96;
    const float* rs3 = (const float*)(smem + RS_OFF + (1 << 8));
    #pragma unroll
    for (int c = 0; c < 32; ++c) {
        const int q = c >> 1;
        const int r = (q & 3) + 8 * (q >> 2) + 4 * half;
        const float mean = rs3[r * 2];
        const float rstd = rs3[r * 2 + 1];
        const size_t roff = (size_t)(m3 + (q & 3) + 8 * (q >> 2)) * 2048 +
                            (size_t)half * 8192 + w * 32 + c31;
        #pragma unroll
        for (int k = 0; k < 4; ++k) {
            const int n = (c & 1) * 4 + k;
            const unsigned hz =
                ((zz[n][c >> 2] >> (16 * ((c >> 1) & 1))) & 0xffffu) << 16;
            const float zf = __builtin_bit_cast(float, hz);
            const float yv = y[roff + n * 256];
            const float zn = (zf - mean) * rstd;
            out[roff + n * 256] = (zn + yv) * yv;
        }
    }
}

// ---------------- round-12 fallback (proven 196 us) ----------------
#define R12_A_OFF    0
#define R12_WQ_LDS   17408
#define R12_ST_OFF   115712
#define R12_RS_OFF   117760
#define R12_RSC_OFF  118016
#define R12_TB_OFF   R12_WQ_LDS
#define R12_SMEM     118144

__global__ __launch_bounds__(THREADS, 2) void fused_r12(
    const float* __restrict__ x, const float* __restrict__ y,
    const float* __restrict__ Bias, const char* __restrict__ Wq,
    const float* __restrict__ sw, float* __restrict__ out) {

    __shared__ __align__(16) char smem[R12_SMEM];

    const int t    = threadIdx.x;
    const int w    = t >> 6;
    const int l    = t & 63;
    const int c31  = l & 31;
    const int half = l >> 5;
    const int m0   = blockIdx.x * 32;

    #pragma unroll
    for (int cc = 0; cc < 2; ++cc)
        #pragma unroll
        for (int i = 0; i < 4; ++i)
            glds16(Wq + (size_t)cc * 32768 + i * 8192 + t * 16,
                   smem + R12_WQ_LDS + cc * 32768 + i * 8192 + w * 1024);

    float* rowscale = (float*)(smem + R12_RSC_OFF);
    {
        const float* xs = x + (size_t)(m0 + w) * INF + l * 8;
        #pragma unroll
        for (int i = 0; i < 4; ++i) {
            const int row = w + 8 * i;
            f32x4 a = ld4(xs + i * 8 * INF), b = ld4(xs + i * 8 * INF + 4);
            float m = 0.f;
            #pragma unroll
            for (int j = 0; j < 4; ++j) m = fmaxf(m, fmaxf(fabsf(a[j]), fabsf(b[j])));
            #pragma unroll
            for (int d = 1; d < 64; d <<= 1) m = fmaxf(m, __shfl_xor(m, d));
            const float inv = m > 0.f ? 127.0f / m : 0.f;
            *(long long*)(smem + R12_A_OFF + l * 264 + ((row ^ (l & 31)) & 31) * 8) =
                quant8(a, b, inv);
            if (l == 0) rowscale[row] = m > 0.f ? m * (1.0f / 127.0f) : 0.f;
        }
    }
    __asm__ volatile("s_waitcnt lgkmcnt(0)" ::: "memory");
    __builtin_amdgcn_s_barrier();

    i32x16 acc[8];
    #pragma unroll
    for (int n = 0; n < 8; ++n) acc[n] = (i32x16)(0);

    #pragma unroll
    for (int c = 0; c < 32; ++c) {
        if (c == 31) { __asm__ volatile("s_waitcnt vmcnt(0)" ::: "memory"); }
        else         { __asm__ volatile("s_waitcnt vmcnt(4)" ::: "memory"); }
        __builtin_amdgcn_s_barrier();
        if (c + 2 < 32) {
            #pragma unroll
            for (int i = 0; i < 4; ++i)
                glds16(Wq + (size_t)(c + 2) * 32768 + i * 8192 + t * 16,
                       smem + R12_WQ_LDS + ((c + 2) % 3) * 32768 + i * 8192 + w * 1024);
        }
        const int k8 = c * 2 + half;
        long long af = *(const long long*)(smem + R12_A_OFF + k8 * 264 +
                                           ((c31 ^ (k8 & 31)) & 31) * 8);
        const char* bb = smem + R12_WQ_LDS + (c % 3) * 32768 + half * 16384 +
                         w * 2048 + c31 * 8;
        #pragma unroll
        for (int n = 0; n < 8; ++n)
            acc[n] = __builtin_amdgcn_mfma_i32_32x32x16_i8(
                af, *(const long long*)(bb + n * 256), acc[n], 0, 0, 0);
    }

    float swv[8], bsv[8];
    #pragma unroll
    for (int n = 0; n < 8; ++n) {
        const int col = n * 256 + w * 32 + c31;
        swv[n] = sw[col];
        bsv[n] = Bias[col];
    }
    float sxv[16];
    #pragma unroll
    for (int q = 0; q < 16; ++q)
        sxv[q] = rowscale[4 * half + (q & 3) + 8 * (q >> 2)];

    float* stats   = (float*)(smem + R12_ST_OFF);
    float* rowstat = (float*)(smem + R12_RS_OFF);

    #pragma unroll
    for (int q = 0; q < 16; ++q) {
        float s1 = 0.f, s2 = 0.f;
        #pragma unroll
        for (int n = 0; n < 8; ++n) {
            float z = fmaf((float)acc[n][q], sxv[q] * swv[n], bsv[n]);
            s1 += z; s2 += z * z;
        }
        #pragma unroll
        for (int d = 1; d < 32; d <<= 1) {
            s1 += __shfl_xor(s1, d);
            s2 += __shfl_xor(s2, d);
        }
        if (c31 == 0) {
            const int r = 4 * half + (q & 3) + 8 * (q >> 2);
            stats[(w * 32 + r) * 2]     = s1;
            stats[(w * 32 + r) * 2 + 1] = s2;
        }
    }
    __syncthreads();
    if (t < 32) {
        float s1 = 0.f, s2 = 0.f;
        #pragma unroll
        for (int wi = 0; wi < 8; ++wi) {
            s1 += stats[(wi * 32 + t) * 2];
            s2 += stats[(wi * 32 + t) * 2 + 1];
        }
        const float mean = s1 * (1.0f / OUTF);
        const float var  = s2 * (1.0f / OUTF) - mean * mean;
        rowstat[t * 2]     = mean;
        rowstat[t * 2 + 1] = rsqrtf(var + 1e-5f);
    }
    __syncthreads();

    float* tbuf = (float*)(smem + R12_TB_OFF);
    #pragma unroll
    for (int p = 0; p < 4; ++p) {
        #pragma unroll
        for (int qq = 0; qq < 4; ++qq) {
            const int q  = 4 * p + qq;
            const int rl = qq + 4 * half;
            #pragma unroll
            for (int n = 0; n < 8; ++n) {
                const int col = n * 256 + w * 32 + c31;
                tbuf[rl * 2052 + col] = fmaf((float)acc[n][q], sxv[q] * swv[n], bsv[n]);
            }
        }
        __syncthreads();
        #pragma unroll
        for (int i = 0; i < 8; ++i) {
            const int r = p * 8 + i;
            f32x4 z4 = *(const f32x4*)(tbuf + i * 2052 + t * 4);
            const float mean = rowstat[r * 2];
            const float rstd = rowstat[r * 2 + 1];
            const size_t grow = (size_t)(m0 + r) * OUTF + t * 4;
            f32x4 yv = ld4(y + grow);
            f32x4 o4;
            #pragma unroll
            for (int j = 0; j < 4; ++j) {
                float zn = (z4[j] - mean) * rstd;
                o4[j] = (zn + yv[j]) * yv[j];
            }
            *(f32x4*)(out + grow) = o4;
        }
        __syncthreads();
    }
}

extern "C" void kernel_launch(void* const* d_in, const int* in_sizes, int n_in,
                              void* d_out, int out_size, void* d_ws, size_t ws_size,
                              hipStream_t stream) {
    const float* x = (const float*)d_in[0];
    const float* y = (const float*)d_in[1];
    const float* W = (const float*)d_in[2];
    const float* B = (const float*)d_in[3];
    float* out = (float*)d_out;

    char*  Wq = (char*)d_ws + WQ_OFF;
    float* sw = (float*)((char*)d_ws + SW_OFF);

    if (ws_size >= (size_t)WS_BIG) {
        char*  xq  = (char*)d_ws + XQ_OFF;
        float* sxg = (float*)((char*)d_ws + SXG_OFF);
        conv_w_kernel<<<OUTF, 64, 0, stream>>>(W, Wq, sw);
        xq_pre<<<BATCH / 32, 256, 0, stream>>>(x, xq, sxg);
        fused_big<<<256, THREADS, 0, stream>>>(y, B, Wq, sw, xq, sxg, out);
    } else {
        conv_w_kernel<<<OUTF, 64, 0, stream>>>(W, Wq, sw);
        fused_r12<<<BATCH / 32, THREADS, 0, stream>>>(x, y, B, Wq, sw, out);
    }
}

// Round 18
// 196.914 us; speedup vs baseline: 2.1206x; 2.1206x over previous
//
#include <hip/hip_runtime.h>
#include <stdint.h>
#include <stddef.h>

// z = x[32768,512] @ W[2048,512]^T + B; per-row instance-norm over 2048;
// out = (z_norm + y) * y.  f32 I/O; GEMM in INT8 MFMA (32x32x16_i8) with
// per-row x-scales and per-col W-scales, dequantized in the epilogue.
//
// Round-18 = proven round-12 kernel (196us) with ONE change: the W glds
// pipeline deepened from 3 buffers / 2 chunks in flight (64KB) to
// 4 buffers / 3 chunks in flight (96KB), counted vmcnt(8) with 8->4->0
// tail. r12's K-phase (~28us/block) sits 4x above its arrival floor
// (~7.6us) and Little's law at the measured ~40GB/s/CU says the 64KB
// in-flight window is the limiter. The N-split/exchange path (r15-r17)
// is abandoned per pre-commit: three protocols raced identically.

typedef float  f32x4  __attribute__((ext_vector_type(4)));
typedef int    i32x16 __attribute__((ext_vector_type(16)));

#define BATCH   32768
#define INF     512
#define OUTF    2048
#define BM      32
#define NBLK    (BATCH / BM)             // 1024
#define THREADS 512
#define WQ_BYTES (OUTF * INF)            // 1 MB int8 W
#define SW_OFF   WQ_BYTES                // sw[2048] f32 after Wq
#define WS_NEED  (WQ_BYTES + OUTF * 4)

// LDS layout (bytes)
#define A_OFF    0                        // [k8(64)][row^swz(32)][8B], stride 264
#define WQ_LDS   16896                    // 4 x 32 KB W chunk buffers
#define ST_OFF   147968                   // [8 waves][32 rows][2] f32
#define RS_OFF   150016                   // [32][2] f32 (mean, rstd)
#define RSC_OFF  150272                   // rowscale[32] f32
#define TB_OFF   WQ_LDS                   // epilogue tbuf [8][2052] f32 (reuse)
#define SMEM_BYTES 150400

__device__ __forceinline__ f32x4 ld4(const float* p) { return *(const f32x4*)p; }

__device__ __forceinline__ void glds16(const void* g, void* l) {
    __builtin_amdgcn_global_load_lds(
        (const __attribute__((address_space(1))) unsigned int*)g,
        (__attribute__((address_space(3))) unsigned int*)l, 16, 0, 0);
}

__device__ __forceinline__ long long quant8(f32x4 a, f32x4 b, float inv) {
    unsigned int lo = 0, hi = 0;
    int q;
    q = (int)__builtin_rintf(a[0] * inv); lo |= (unsigned)(q & 255);
    q = (int)__builtin_rintf(a[1] * inv); lo |= (unsigned)(q & 255) << 8;
    q = (int)__builtin_rintf(a[2] * inv); lo |= (unsigned)(q & 255) << 16;
    q = (int)__builtin_rintf(a[3] * inv); lo |= (unsigned)(q & 255) << 24;
    q = (int)__builtin_rintf(b[0] * inv); hi |= (unsigned)(q & 255);
    q = (int)__builtin_rintf(b[1] * inv); hi |= (unsigned)(q & 255) << 8;
    q = (int)__builtin_rintf(b[2] * inv); hi |= (unsigned)(q & 255) << 16;
    q = (int)__builtin_rintf(b[3] * inv); hi |= (unsigned)(q & 255) << 24;
    return (long long)(((unsigned long long)hi << 32) | lo);
}

// Prepass: W f32 [2048,512] -> Wq int8 chunk-major + sw[2048] f32 scales.
// chunk c = s-step (K=16) = 32 KB: off = c*32768 + half*16384 + w*2048
//         + n*256 + c31*8  (col = n*256 + w*32 + c31; k = c*16 + half*8 + j)
__global__ __launch_bounds__(64) void conv_w_kernel(const float* __restrict__ W,
                                                    char* __restrict__ Wq,
                                                    float* __restrict__ sw) {
    const int o = blockIdx.x;        // col
    const int l = threadIdx.x;       // k8 = l
    const float* src = W + (size_t)o * INF + l * 8;
    f32x4 a = ld4(src), b = ld4(src + 4);
    float m = 0.f;
    #pragma unroll
    for (int j = 0; j < 4; ++j) m = fmaxf(m, fmaxf(fabsf(a[j]), fabsf(b[j])));
    #pragma unroll
    for (int d = 1; d < 64; d <<= 1) m = fmaxf(m, __shfl_xor(m, d));
    const float inv = m > 0.f ? 127.0f / m : 0.f;
    long long v = quant8(a, b, inv);
    const int s = l >> 1, half = l & 1;
    size_t off = (size_t)s * 32768 + half * 16384 +
                 ((o >> 5) & 7) * 2048 + (o >> 8) * 256 + (o & 31) * 8;
    *(long long*)(Wq + off) = v;
    if (l == 0) sw[o] = m > 0.f ? m * (1.0f / 127.0f) : 0.f;
}

// A-frag (32x32x16_i8): lane l -> A[row=l&31][k = c*16 + (l>>5)*8 + j]
// C-frag: col = lane&31, row = (q&3) + 8*(q>>2) + 4*(lane>>5), q=0..15
// Wave w owns cols col(n) = n*256 + w*32 + c31, n = 0..7.
__global__ __launch_bounds__(THREADS, 2) void fused_kernel(
    const float* __restrict__ x, const float* __restrict__ y,
    const float* __restrict__ Bias, const char* __restrict__ Wq,
    const float* __restrict__ sw, float* __restrict__ out) {

    __shared__ __align__(16) char smem[SMEM_BYTES];

    const int t    = threadIdx.x;
    const int w    = t >> 6;
    const int l    = t & 63;
    const int c31  = l & 31;
    const int half = l >> 5;
    const int m0   = blockIdx.x * BM;

    // ---- issue W chunks 0,1,2 into LDS bufs 0,1,2 ----
    #pragma unroll
    for (int cc = 0; cc < 3; ++cc)
        #pragma unroll
        for (int i = 0; i < 4; ++i)
            glds16(Wq + (size_t)cc * 32768 + i * 8192 + t * 16,
                   smem + WQ_LDS + cc * 32768 + i * 8192 + w * 1024);

    // ---- stage A: quantize x rows to int8 in LDS; rowscale[32] ----
    float* rowscale = (float*)(smem + RSC_OFF);
    {
        const float* xs = x + (size_t)(m0 + w) * INF + l * 8;
        #pragma unroll
        for (int i = 0; i < 4; ++i) {      // row = w + 8i; lane l = k8 plane
            const int row = w + 8 * i;
            f32x4 a = ld4(xs + i * 8 * INF), b = ld4(xs + i * 8 * INF + 4);
            float m = 0.f;
            #pragma unroll
            for (int j = 0; j < 4; ++j) m = fmaxf(m, fmaxf(fabsf(a[j]), fabsf(b[j])));
            #pragma unroll
            for (int d = 1; d < 64; d <<= 1) m = fmaxf(m, __shfl_xor(m, d));
            const float inv = m > 0.f ? 127.0f / m : 0.f;
            *(long long*)(smem + A_OFF + l * 264 + ((row ^ (l & 31)) & 31) * 8) =
                quant8(a, b, inv);
            if (l == 0) rowscale[row] = m > 0.f ? m * (1.0f / 127.0f) : 0.f;
        }
    }
    __asm__ volatile("s_waitcnt lgkmcnt(0)" ::: "memory");  // A+rowscale visible
    __builtin_amdgcn_s_barrier();

    i32x16 acc[8];
    #pragma unroll
    for (int n = 0; n < 8; ++n) acc[n] = (i32x16)(0);

    // ---- K loop: 32 chunks, 4-buffer pipeline, 3 chunks (96KB) in flight.
    //      vmcnt(8) guarantees chunk c landed while c+1,c+2 stay in flight. ----
    #pragma unroll
    for (int c = 0; c < 32; ++c) {
        if (c <= 29)      { __asm__ volatile("s_waitcnt vmcnt(8)" ::: "memory"); }
        else if (c == 30) { __asm__ volatile("s_waitcnt vmcnt(4)" ::: "memory"); }
        else              { __asm__ volatile("s_waitcnt vmcnt(0)" ::: "memory"); }
        __builtin_amdgcn_s_barrier();   // chunk c visible to all; buf (c+3)%4 free
        if (c + 3 < 32) {
            #pragma unroll
            for (int i = 0; i < 4; ++i)
                glds16(Wq + (size_t)(c + 3) * 32768 + i * 8192 + t * 16,
                       smem + WQ_LDS + ((c + 3) % 4) * 32768 + i * 8192 + w * 1024);
        }
        const int k8 = c * 2 + half;
        long long af = *(const long long*)(smem + A_OFF + k8 * 264 +
                                           ((c31 ^ (k8 & 31)) & 31) * 8);
        const char* bb = smem + WQ_LDS + (c % 4) * 32768 + half * 16384 +
                         w * 2048 + c31 * 8;
        #pragma unroll
        for (int n = 0; n < 8; ++n) {
            long long bf = *(const long long*)(bb + n * 256);
            acc[n] = __builtin_amdgcn_mfma_i32_32x32x16_i8(af, bf, acc[n], 0, 0, 0);
        }
    }

    // ---- dequant scales ----
    float swv[8], bsv[8];
    #pragma unroll
    for (int n = 0; n < 8; ++n) {
        const int col = n * 256 + w * 32 + c31;
        swv[n] = sw[col];
        bsv[n] = Bias[col];
    }
    float sxv[16];
    #pragma unroll
    for (int q = 0; q < 16; ++q)
        sxv[q] = rowscale[4 * half + (q & 3) + 8 * (q >> 2)];

    float* stats   = (float*)(smem + ST_OFF);   // [8][32][2]
    float* rowstat = (float*)(smem + RS_OFF);   // [32][2]

    // ---- per-row stats (z recomputed from acc on the fly) ----
    #pragma unroll
    for (int q = 0; q < 16; ++q) {
        float s1 = 0.f, s2 = 0.f;
        #pragma unroll
        for (int n = 0; n < 8; ++n) {
            float z = fmaf((float)acc[n][q], sxv[q] * swv[n], bsv[n]);
            s1 += z; s2 += z * z;
        }
        #pragma unroll
        for (int d = 1; d < 32; d <<= 1) {
            s1 += __shfl_xor(s1, d);
            s2 += __shfl_xor(s2, d);
        }
        if (c31 == 0) {
            const int r = 4 * half + (q & 3) + 8 * (q >> 2);
            stats[(w * 32 + r) * 2]     = s1;
            stats[(w * 32 + r) * 2 + 1] = s2;
        }
    }
    __syncthreads();

    if (t < 32) {
        float s1 = 0.f, s2 = 0.f;
        #pragma unroll
        for (int wi = 0; wi < 8; ++wi) {
            s1 += stats[(wi * 32 + t) * 2];
            s2 += stats[(wi * 32 + t) * 2 + 1];
        }
        const float mean = s1 * (1.0f / OUTF);
        const float var  = s2 * (1.0f / OUTF) - mean * mean;
        rowstat[t * 2]     = mean;
        rowstat[t * 2 + 1] = rsqrtf(var + 1e-5f);
    }
    __syncthreads();

    // ---- epilogue: 4 phases of 8 rows; block LDS transpose (tbuf reuses
    //      W buffers) -> full-row 8KB float4 bursts on y/out ----
    float* tbuf = (float*)(smem + TB_OFF);   // [8][2052]
    #pragma unroll
    for (int p = 0; p < 4; ++p) {
        #pragma unroll
        for (int qq = 0; qq < 4; ++qq) {
            const int q  = 4 * p + qq;
            const int rl = qq + 4 * half;
            #pragma unroll
            for (int n = 0; n < 8; ++n) {
                const int col = n * 256 + w * 32 + c31;
                tbuf[rl * 2052 + col] = fmaf((float)acc[n][q], sxv[q] * swv[n], bsv[n]);
            }
        }
        __syncthreads();
        #pragma unroll
        for (int i = 0; i < 8; ++i) {
            const int r = p * 8 + i;
            f32x4 z4 = *(const f32x4*)(tbuf + i * 2052 + t * 4);
            const float mean = rowstat[r * 2];
            const float rstd = rowstat[r * 2 + 1];
            const size_t grow = (size_t)(m0 + r) * OUTF + t * 4;
            f32x4 yv = ld4(y + grow);
            f32x4 o4;
            #pragma unroll
            for (int j = 0; j < 4; ++j) {
                float zn = (z4[j] - mean) * rstd;
                o4[j] = (zn + yv[j]) * yv[j];
            }
            *(f32x4*)(out + grow) = o4;
        }
        __syncthreads();
    }
}

// Correctness-only fallback if workspace is too small (never expected).
__global__ __launch_bounds__(256) void naive_kernel(
    const float* __restrict__ x, const float* __restrict__ y,
    const float* __restrict__ W, const float* __restrict__ Bias,
    float* __restrict__ out) {
    const int row = blockIdx.x, t = threadIdx.x;
    __shared__ float xs[INF];
    __shared__ float zs[OUTF];
    __shared__ float red1[4], red2[4];
    for (int i = t; i < INF; i += 256) xs[i] = x[(size_t)row * INF + i];
    __syncthreads();
    for (int c = t; c < OUTF; c += 256) {
        const float* wr = W + (size_t)c * INF;
        float s = 0.f;
        for (int k = 0; k < INF; ++k) s += xs[k] * wr[k];
        zs[c] = s + Bias[c];
    }
    __syncthreads();
    float s1 = 0.f, s2 = 0.f;
    for (int c = t; c < OUTF; c += 256) { float v = zs[c]; s1 += v; s2 += v * v; }
    for (int d = 1; d < 64; d <<= 1) { s1 += __shfl_xor(s1, d); s2 += __shfl_xor(s2, d); }
    if ((t & 63) == 0) { red1[t >> 6] = s1; red2[t >> 6] = s2; }
    __syncthreads();
    float ts1 = red1[0] + red1[1] + red1[2] + red1[3];
    float ts2 = red2[0] + red2[1] + red2[2] + red2[3];
    const float mean = ts1 * (1.0f / OUTF);
    const float rstd = rsqrtf(ts2 * (1.0f / OUTF) - mean * mean + 1e-5f);
    for (int c = t; c < OUTF; c += 256) {
        const size_t off = (size_t)row * OUTF + c;
        float yv = y[off];
        float zn = (zs[c] - mean) * rstd;
        out[off] = (zn + yv) * yv;
    }
}

extern "C" void kernel_launch(void* const* d_in, const int* in_sizes, int n_in,
                              void* d_out, int out_size, void* d_ws, size_t ws_size,
                              hipStream_t stream) {
    const float* x = (const float*)d_in[0];
    const float* y = (const float*)d_in[1];
    const float* W = (const float*)d_in[2];
    const float* B = (const float*)d_in[3];
    float* out = (float*)d_out;

    if (ws_size >= (size_t)WS_NEED) {
        char*  Wq = (char*)d_ws;
        float* sw = (float*)((char*)d_ws + SW_OFF);
        conv_w_kernel<<<OUTF, 64, 0, stream>>>(W, Wq, sw);
        fused_kernel<<<NBLK, THREADS, 0, stream>>>(x, y, B, Wq, sw, out);
    } else {
        naive_kernel<<<BATCH, 256, 0, stream>>>(x, y, W, B, out);
    }
}